// Round 4
// baseline (105.051 us; speedup 1.0000x reference)
//
#include <hip/hip_runtime.h>

#define B_ 16
#define QN 256
#define KN 256
#define DN 256
#define HN 256

#define LOG2E 1.4426950408889634f
#define TWOLOG2E 2.8853900817779268f  // exp2(x*this) = e^{2x}

// ---------------- Kernel A (fused): Y[r][h] = (sum_d X[r][d]*W[d][h]) * scale --------
// 16 rows per block (W re-read amortized over 16 rows -> L2 traffic halved vs 8-row).
// First half of grid does queries@Wq, second half keys@Wk.
__global__ __launch_bounds__(256) void proj_kernel(const float* __restrict__ Xq,
                                                   const float* __restrict__ Xk,
                                                   const float* __restrict__ Wq,
                                                   const float* __restrict__ Wk,
                                                   float* __restrict__ Yq,
                                                   float* __restrict__ Yk,
                                                   float scale) {
    const int nb = (int)gridDim.x >> 1;
    int blk = blockIdx.x;
    const float* X;
    const float* W;
    float* Y;
    if (blk < nb) { X = Xq; W = Wq; Y = Yq; }
    else          { X = Xk; W = Wk; Y = Yk; blk -= nb; }
    const int row0 = blk * 16;

    __shared__ float xl[16][DN];
    const int tid = threadIdx.x;

    {
        const float4* src = (const float4*)(X + (size_t)row0 * DN);
        float4* dst = (float4*)&xl[0][0];
#pragma unroll
        for (int i = 0; i < 4; ++i) dst[tid + 256 * i] = src[tid + 256 * i];
    }
    __syncthreads();

    const int h = tid;
    float acc[16];
#pragma unroll
    for (int r = 0; r < 16; ++r) acc[r] = 0.f;

    for (int d0 = 0; d0 < DN; d0 += 4) {
        float w0 = W[(size_t)(d0 + 0) * HN + h];
        float w1 = W[(size_t)(d0 + 1) * HN + h];
        float w2 = W[(size_t)(d0 + 2) * HN + h];
        float w3 = W[(size_t)(d0 + 3) * HN + h];
#pragma unroll
        for (int r = 0; r < 16; ++r) {
            float4 x = *(const float4*)&xl[r][d0];  // wave-uniform -> LDS broadcast
            acc[r] = fmaf(x.x, w0, acc[r]);
            acc[r] = fmaf(x.y, w1, acc[r]);
            acc[r] = fmaf(x.z, w2, acc[r]);
            acc[r] = fmaf(x.w, w3, acc[r]);
        }
    }
#pragma unroll
    for (int r = 0; r < 16; ++r)
        Y[(size_t)(row0 + r) * HN + h] = acc[r] * scale;
}

// ------------- Kernel B: ACC[b][q][k] = sum_h wv[h] * rcp(1 + exp2(qs+ks)) -----------
// true score = Wsum - 2*ACC; Wsum constant -> softmax-invariant, never formed.
// Tile 16q x 64k; thread owns 1q x 4 consecutive k. Inner loop hand-batched in windows
// of 8 h-steps: 8x b128 LDS loads up front, then 32 independent exp2, then 32 rcp+fma.
// __launch_bounds__(256,2): 128-VGPR budget so the whole window stays in registers.
__global__ __launch_bounds__(256, 2) void score_kernel(const float* __restrict__ QS,
                                                       const float* __restrict__ KS,
                                                       const float* __restrict__ wv,
                                                       const int* __restrict__ lens,
                                                       float* __restrict__ ACC) {
    const int b = blockIdx.z;
    const int k0 = blockIdx.x * 64;
    const int q0 = blockIdx.y * 16;
    const int len = lens[b];
    if (k0 >= len) return;  // whole tile masked -> never read downstream

    __shared__ float qs_l[16][68];
    __shared__ float ksT[64][68];   // TRANSPOSED: ksT[h][k]
    __shared__ float wv_l[64];

    const int tid = threadIdx.x;
    const int q = tid >> 4;     // 0..15
    const int kg = tid & 15;    // owns k = 4*kg .. 4*kg+3

    float acc0 = 0.f, acc1 = 0.f, acc2 = 0.f, acc3 = 0.f;

    const float* qbase = QS + ((size_t)b * QN + q0) * HN;
    const float* kbase = KS + ((size_t)b * KN + k0) * HN;

    const int sr = tid >> 4, sc4 = (tid & 15) << 2;   // qs staging coords
    const int kk = tid >> 2, kp = (tid & 3) << 4;     // ksT staging: k row, h-part

    for (int h0 = 0; h0 < HN; h0 += 64) {
        *(float4*)&qs_l[sr][sc4] = *(const float4*)&qbase[(size_t)sr * HN + h0 + sc4];
#pragma unroll
        for (int j = 0; j < 4; ++j) {
            float4 v = *(const float4*)&kbase[(size_t)kk * HN + h0 + kp + 4 * j];
            ksT[kp + 4 * j + 0][kk] = v.x;
            ksT[kp + 4 * j + 1][kk] = v.y;
            ksT[kp + 4 * j + 2][kk] = v.z;
            ksT[kp + 4 * j + 3][kk] = v.w;
        }
        if (tid < 16) *(float4*)&wv_l[tid << 2] = *(const float4*)&wv[h0 + (tid << 2)];
        __syncthreads();

#pragma unroll
        for (int hb = 0; hb < 64; hb += 8) {
            float4 kv[8];
            float qv[8], wl[8];
#pragma unroll
            for (int u = 0; u < 8; ++u) kv[u] = *(const float4*)&ksT[hb + u][kg << 2];
#pragma unroll
            for (int u = 0; u < 8; ++u) {
                qv[u] = qs_l[q][hb + u];   // broadcast
                wl[u] = wv_l[hb + u];      // broadcast
            }
            float e[32];
#pragma unroll
            for (int u = 0; u < 8; ++u) {
                e[4 * u + 0] = __builtin_amdgcn_exp2f(qv[u] + kv[u].x);
                e[4 * u + 1] = __builtin_amdgcn_exp2f(qv[u] + kv[u].y);
                e[4 * u + 2] = __builtin_amdgcn_exp2f(qv[u] + kv[u].z);
                e[4 * u + 3] = __builtin_amdgcn_exp2f(qv[u] + kv[u].w);
            }
#pragma unroll
            for (int u = 0; u < 8; ++u) {
                acc0 = fmaf(wl[u], __builtin_amdgcn_rcpf(1.f + e[4 * u + 0]), acc0);
                acc1 = fmaf(wl[u], __builtin_amdgcn_rcpf(1.f + e[4 * u + 1]), acc1);
                acc2 = fmaf(wl[u], __builtin_amdgcn_rcpf(1.f + e[4 * u + 2]), acc2);
                acc3 = fmaf(wl[u], __builtin_amdgcn_rcpf(1.f + e[4 * u + 3]), acc3);
            }
        }
        __syncthreads();
    }

    *(float4*)&ACC[((size_t)b * QN + q0 + q) * KN + k0 + (kg << 2)] =
        make_float4(acc0, acc1, acc2, acc3);
}

// ------------- Kernel C: masked softmax over (-2*ACC) then attn @ values -------------
__global__ __launch_bounds__(256) void softmax_pv_kernel(const float* __restrict__ ACC,
                                                         const float* __restrict__ V,
                                                         const int* __restrict__ lens,
                                                         float* __restrict__ OUT) {
    const int b = blockIdx.y;
    const int q0 = blockIdx.x * 8;
    const int len = lens[b];

    __shared__ float sl[8][256];
    const int tid = threadIdx.x;

    const float* src = ACC + ((size_t)b * QN + q0) * KN;
#pragma unroll
    for (int i = tid; i < 8 * 256; i += 256) {
        int r = i >> 8, k = i & 255;
        float v = src[r * KN + k];
        sl[r][k] = (k < len) ? (-2.f * v) : -1e6f;
    }
    __syncthreads();

    const int wave = tid >> 6, lane = tid & 63;
    for (int r = wave; r < 8; r += 4) {
        float x0 = sl[r][lane];
        float x1 = sl[r][lane + 64];
        float x2 = sl[r][lane + 128];
        float x3 = sl[r][lane + 192];
        float m = fmaxf(fmaxf(x0, x1), fmaxf(x2, x3));
#pragma unroll
        for (int off = 32; off; off >>= 1) m = fmaxf(m, __shfl_xor(m, off, 64));
        float p0 = __builtin_amdgcn_exp2f((x0 - m) * LOG2E);
        float p1 = __builtin_amdgcn_exp2f((x1 - m) * LOG2E);
        float p2 = __builtin_amdgcn_exp2f((x2 - m) * LOG2E);
        float p3 = __builtin_amdgcn_exp2f((x3 - m) * LOG2E);
        float s = (p0 + p1) + (p2 + p3);
#pragma unroll
        for (int off = 32; off; off >>= 1) s += __shfl_xor(s, off, 64);
        float inv = 1.f / s;
        sl[r][lane] = p0 * inv;
        sl[r][lane + 64] = p1 * inv;
        sl[r][lane + 128] = p2 * inv;
        sl[r][lane + 192] = p3 * inv;
    }
    __syncthreads();

    const int d = tid;
    float out_acc[8];
#pragma unroll
    for (int r = 0; r < 8; ++r) out_acc[r] = 0.f;

    const float* vbase = V + (size_t)b * KN * DN + d;
    const int len4 = (len + 3) & ~3;
    for (int k = 0; k < len4; k += 4) {
        float v0 = vbase[(size_t)(k + 0) * DN];
        float v1 = vbase[(size_t)(k + 1) * DN];
        float v2 = vbase[(size_t)(k + 2) * DN];
        float v3 = vbase[(size_t)(k + 3) * DN];
#pragma unroll
        for (int r = 0; r < 8; ++r) {
            float4 a = *(const float4*)&sl[r][k];
            out_acc[r] = fmaf(a.x, v0, out_acc[r]);
            out_acc[r] = fmaf(a.y, v1, out_acc[r]);
            out_acc[r] = fmaf(a.z, v2, out_acc[r]);
            out_acc[r] = fmaf(a.w, v3, out_acc[r]);
        }
    }
    float* obase = OUT + ((size_t)b * QN + q0) * DN + d;
#pragma unroll
    for (int r = 0; r < 8; ++r) obase[(size_t)r * DN] = out_acc[r];
}

extern "C" void kernel_launch(void* const* d_in, const int* in_sizes, int n_in,
                              void* d_out, int out_size, void* d_ws, size_t ws_size,
                              hipStream_t stream) {
    const float* queries = (const float*)d_in[0];
    const float* keys    = (const float*)d_in[1];
    const float* values  = (const float*)d_in[2];
    const int*   lens    = (const int*)d_in[3];
    const float* Wq      = (const float*)d_in[4];
    const float* Wk      = (const float*)d_in[5];
    const float* wv      = (const float*)d_in[6];
    float* out = (float*)d_out;

    float* qs  = (float*)d_ws;                       // [B,Q,H]  4 MB
    float* ks  = qs + (size_t)B_ * QN * HN;          // [B,K,H]  4 MB
    float* acc = ks + (size_t)B_ * KN * HN;          // [B,Q,K]  4 MB

    proj_kernel<<<(B_ * QN + B_ * KN) / 16, 256, 0, stream>>>(
        queries, keys, Wq, Wk, qs, ks, TWOLOG2E);

    dim3 gB(KN / 64, QN / 16, B_);
    score_kernel<<<gB, 256, 0, stream>>>(qs, ks, wv, lens, acc);

    dim3 gC(QN / 8, B_);
    softmax_pv_kernel<<<gC, 256, 0, stream>>>(acc, values, lens, out);
}